// Round 3
// baseline (10507.727 us; speedup 1.0000x reference)
//
#include <hip/hip_runtime.h>

// LSTM_87771951661891: persistent kernel (plain launch, own flag barriers).
// B=256, T=512, H=512, I=256. Grid 256 blocks = 16 row-groups x 16 j-blocks.
// Each block: rows [mg*16, mg*16+16), hidden cols [jb*32, jb*32+32)
//   -> gate cols {g*512 + j : g in 0..3}.
// U_w slice lives in VGPRs as MFMA B-fragments (loaded once).
// h state double-buffered in d_ws as split bf16 (hi+lo planes) for accuracy.
// Per-step sync: 16 device-scope flags per row-group (monotonic values).
// __launch_bounds__(256,1) -> 1 block/CU -> all 256 blocks co-resident.

#define TN 512
#define BM 256
#define HD 512
#define ID 256

typedef __attribute__((ext_vector_type(8))) __bf16 bf16x8;
typedef __attribute__((ext_vector_type(4))) float f32x4;

#define FENCE_REL() __builtin_amdgcn_fence(__ATOMIC_RELEASE, "agent")
#define FENCE_ACQ() __builtin_amdgcn_fence(__ATOMIC_ACQUIRE, "agent")

__device__ __forceinline__ float sigm(float x) { return 1.f / (1.f + __expf(-x)); }
__device__ __forceinline__ float tanh_fast(float x) { return 1.f - 2.f / (__expf(2.f * x) + 1.f); }

__global__ void __launch_bounds__(256, 1)
lstm_persist(const float* __restrict__ x_in, const int* __restrict__ bs_in,
             const float* __restrict__ h0, const float* __restrict__ c0,
             const float* __restrict__ tau_p, const float* __restrict__ Ww,
             const float* __restrict__ Wb, const float* __restrict__ Uw,
             float* __restrict__ out, __bf16* __restrict__ hbuf,
             int* __restrict__ flags)
{
    __shared__ int   bs_lds[TN];
    __shared__ float x0_lds[16][ID];     // prologue only
    __shared__ float hn_lds[16][32];     // per-step h_new tile (fp32)
    __shared__ float hxy[16][2];         // fp32 exact xcorr side-channel (jb==0)

    const int tid  = threadIdx.x;
    const int lane = tid & 63;
    const int w    = tid >> 6;           // wave 0..3
    const int bid  = blockIdx.x;
    const int mg   = bid >> 4;           // row-group
    const int jb   = bid & 15;           // j-block
    const int row0 = mg * 16;
    const int j0   = jb * 32;
    const int l15  = lane & 15;
    const int kg   = lane >> 4;          // 0..3 (k-chunk / row-quad id)
    const int jjq  = l15 >> 2;           // 0..3
    const int gq   = lane & 3;           // gate held pre-butterfly (0:i 1:f 2:g 3:o)
    const float tau = tau_p[0];

    // ---------------- prologue ----------------
    for (int i = tid; i < TN; i += 256) bs_lds[i] = bs_in[i];
    for (int s = tid; s < 16 * (ID / 4); s += 256) {
        int r = s >> 6, cs = s & 63;
        reinterpret_cast<float4*>(&x0_lds[r][0])[cs] =
            reinterpret_cast<const float4*>(x_in + (size_t)(row0 + r) * ID)[cs];
    }
    __syncthreads();

    // Gx = x0 @ Ww + Wb  (fp32, one-time). Column for (f, lane): gq*512 + j0 + 8w + 4f + jjq
    const int jjA   = 8 * w + jjq;
    const int ucolA = gq * HD + j0 + jjA;     // f = 0
    const int ucolB = ucolA + 4;              // f = 1
    float gxv[2][4];
    {
        float a[2][4] = {};
        for (int k = 0; k < ID; ++k) {
            float xv0 = x0_lds[kg * 4 + 0][k];
            float xv1 = x0_lds[kg * 4 + 1][k];
            float xv2 = x0_lds[kg * 4 + 2][k];
            float xv3 = x0_lds[kg * 4 + 3][k];
            float w0 = Ww[(size_t)k * 2048 + ucolA];
            float w1 = Ww[(size_t)k * 2048 + ucolB];
            a[0][0] += xv0 * w0; a[0][1] += xv1 * w0; a[0][2] += xv2 * w0; a[0][3] += xv3 * w0;
            a[1][0] += xv0 * w1; a[1][1] += xv1 * w1; a[1][2] += xv2 * w1; a[1][3] += xv3 * w1;
        }
        float b0 = Wb[ucolA], b1 = Wb[ucolB];
        #pragma unroll
        for (int r = 0; r < 4; ++r) { gxv[0][r] = a[0][r] + b0; gxv[1][r] = a[1][r] + b1; }
    }

    // U slice -> registers as MFMA B-fragments (B[k][col]: lane holds 8 k at kg*8, col l15)
    bf16x8 ub[2][16];
    #pragma unroll
    for (int f = 0; f < 2; ++f) {
        const int ucol = f ? ucolB : ucolA;
        #pragma unroll
        for (int ki = 0; ki < 16; ++ki) {
            const int kb = ki * 32 + kg * 8;
            bf16x8 v;
            #pragma unroll
            for (int e = 0; e < 8; ++e) v[e] = (__bf16)Uw[(size_t)(kb + e) * 2048 + ucol];
            ub[f][ki] = v;
        }
    }

    // c state (fp32, register-resident; quad-redundant consistent copies)
    float creg[2][4];
    #pragma unroll
    for (int f = 0; f < 2; ++f) {
        const int jc = j0 + 8 * w + 4 * f + jjq;
        #pragma unroll
        for (int r = 0; r < 4; ++r)
            creg[f][r] = c0[(size_t)(row0 + kg * 4 + r) * HD + jc];
    }

    // h_buf[0] init: split bf16 hi/lo planes; hxy fp32 init (jb==0)
    if (w == 0) {
        const int r = lane >> 2, seg = lane & 3;
        const float* src = h0 + (size_t)(row0 + r) * HD + j0 + seg * 8;
        float4 v0 = *reinterpret_cast<const float4*>(src);
        float4 v1 = *reinterpret_cast<const float4*>(src + 4);
        float hv[8] = {v0.x, v0.y, v0.z, v0.w, v1.x, v1.y, v1.z, v1.w};
        bf16x8 svh, svl;
        #pragma unroll
        for (int e = 0; e < 8; ++e) {
            __bf16 hb = (__bf16)hv[e];
            svh[e] = hb; svl[e] = (__bf16)(hv[e] - (float)hb);
        }
        const size_t off = (size_t)(row0 + r) * HD + j0 + seg * 8;
        *reinterpret_cast<bf16x8*>(hbuf + off) = svh;
        *reinterpret_cast<bf16x8*>(hbuf + (size_t)BM * HD + off) = svl;
        if (jb == 0 && seg == 0) { hxy[r][0] = v0.x; hxy[r][1] = v0.y; }
    }
    __syncthreads();
    if (w == 0) {
        FENCE_REL();
        if (lane == 0)
            __hip_atomic_store(&flags[mg * 32 + jb], 1, __ATOMIC_RELAXED, __HIP_MEMORY_SCOPE_AGENT);
    }
    for (;;) {
        int v = __hip_atomic_load(&flags[mg * 32 + l15], __ATOMIC_RELAXED, __HIP_MEMORY_SCOPE_AGENT);
        if (__all(v >= 1)) break;
        __builtin_amdgcn_s_sleep(1);
    }
    FENCE_ACQ();

    // ---------------- main sequential loop ----------------
    for (int t = 0; t < TN; ++t) {
        const __bf16* base_p = hbuf + (size_t)(t & 1) * (2 * BM * HD);
        __bf16*       base_n = hbuf + (size_t)((t + 1) & 1) * (2 * BM * HD);
        const int bs_t = bs_lds[t];

        // exact fp32 xcorr recurrence for cols 0,1 (all rows), jb==0/wave0 only
        if (jb == 0 && w == 0 && l15 == 0 && t != 0) {
            #pragma unroll
            for (int r = 0; r < 4; ++r) {
                int m = kg * 4 + r;
                float xs0 = hxy[m][0], xs1 = hxy[m][1];
                hxy[m][0] = xs0 + tau * (1.5f * xs0 + 0.66666667f * xs1);
                hxy[m][1] = xs1 + tau * (-1.5f * xs0);
            }
        }

        // A fragments: split hi/lo bf16, direct from global (A[row=l15][k=kg*8+e])
        bf16x8 ah[16], al[16];
        const __bf16* arow_h = base_p + (size_t)(row0 + l15) * HD;
        const __bf16* arow_l = arow_h + (size_t)BM * HD;
        #pragma unroll
        for (int ki = 0; ki < 16; ++ki) {
            ah[ki] = *reinterpret_cast<const bf16x8*>(arow_h + ki * 32 + kg * 8);
            al[ki] = *reinterpret_cast<const bf16x8*>(arow_l + ki * 32 + kg * 8);
        }
        // read-side xcorr on k=0,1 (applies to all rows; t!=0)
        if (t != 0 && kg == 0) {
            float xs0 = (float)ah[0][0] + (float)al[0][0];
            float xs1 = (float)ah[0][1] + (float)al[0][1];
            float n0 = xs0 + tau * (1.5f * xs0 + 0.66666667f * xs1);
            float n1 = xs1 + tau * (-1.5f * xs0);
            __bf16 b0 = (__bf16)n0; ah[0][0] = b0; al[0][0] = (__bf16)(n0 - (float)b0);
            __bf16 b1 = (__bf16)n1; ah[0][1] = b1; al[0][1] = (__bf16)(n1 - (float)b1);
        }

        // gates = (A_hi + A_lo) @ U  via MFMA, acc fp32
        f32x4 acc[2] = {{0.f,0.f,0.f,0.f},{0.f,0.f,0.f,0.f}};
        #pragma unroll
        for (int ki = 0; ki < 16; ++ki) {
            acc[0] = __builtin_amdgcn_mfma_f32_16x16x32_bf16(ah[ki], ub[0][ki], acc[0], 0, 0, 0);
            acc[1] = __builtin_amdgcn_mfma_f32_16x16x32_bf16(ah[ki], ub[1][ki], acc[1], 0, 0, 0);
            acc[0] = __builtin_amdgcn_mfma_f32_16x16x32_bf16(al[ki], ub[0][ki], acc[0], 0, 0, 0);
            acc[1] = __builtin_amdgcn_mfma_f32_16x16x32_bf16(al[ki], ub[1][ki], acc[1], 0, 0, 0);
        }

        // pointwise: quad butterfly gathers i,f,g,o; update c; stash h_new
        const int qb = lane & ~3;
        #pragma unroll
        for (int f = 0; f < 2; ++f) {
            #pragma unroll
            for (int r = 0; r < 4; ++r) {
                float v  = acc[f][r] + gxv[f][r];
                float gi = __shfl(v, qb + 0);
                float gf = __shfl(v, qb + 1);
                float gg = __shfl(v, qb + 2);
                float go = __shfl(v, qb + 3);
                float cn = sigm(gf) * creg[f][r] + sigm(gi) * tanh_fast(gg);
                float hn = sigm(go) * tanh_fast(cn);
                int m = kg * 4 + r;
                bool active = (row0 + m) < bs_t;
                if (active) creg[f][r] = cn;
                if (gq == 0) {
                    int jj = 8 * w + 4 * f + jjq;
                    hn_lds[m][jj] = hn;
                    if (jb == 0 && jj < 2 && active) hxy[m][jj] = hn;
                }
            }
        }
        __syncthreads();

        // store phase (wave0): h_next (split bf16) + outputs[t]
        if (w == 0) {
            const int r = lane >> 2, seg = lane & 3;
            const int rowg = row0 + r;
            const bool act = rowg < bs_t;
            const size_t off = (size_t)rowg * HD + j0 + seg * 8;
            bf16x8 pvh = *reinterpret_cast<const bf16x8*>(base_p + off);
            bf16x8 pvl = *reinterpret_cast<const bf16x8*>(base_p + (size_t)BM * HD + off);
            float hv[8];
            #pragma unroll
            for (int e = 0; e < 8; ++e) {
                int jgl = j0 + seg * 8 + e;
                float prevf = (float)pvh[e] + (float)pvl[e];
                float nv = hn_lds[r][seg * 8 + e];
                hv[e] = act ? nv : ((jgl < 2) ? hxy[r][jgl] : prevf);
            }
            bf16x8 svh, svl;
            #pragma unroll
            for (int e = 0; e < 8; ++e) {
                __bf16 hb = (__bf16)hv[e];
                svh[e] = hb; svl[e] = (__bf16)(hv[e] - (float)hb);
            }
            *reinterpret_cast<bf16x8*>(base_n + off) = svh;
            *reinterpret_cast<bf16x8*>(base_n + (size_t)BM * HD + off) = svl;

            float ov[8];
            #pragma unroll
            for (int e = 0; e < 8; ++e) ov[e] = act ? hn_lds[r][seg * 8 + e] : 0.f;
            float4 q0, q1;
            q0.x = ov[0]; q0.y = ov[1]; q0.z = ov[2]; q0.w = ov[3];
            q1.x = ov[4]; q1.y = ov[5]; q1.z = ov[6]; q1.w = ov[7];
            float* op = out + (size_t)t * (BM * HD) + off;
            *reinterpret_cast<float4*>(op)     = q0;
            *reinterpret_cast<float4*>(op + 4) = q1;

            FENCE_REL();
            if (lane == 0)
                __hip_atomic_store(&flags[mg * 32 + jb], t + 2, __ATOMIC_RELAXED, __HIP_MEMORY_SCOPE_AGENT);
        }

        // row-group barrier: all waves spin on the group's 16 flags
        {
            const int target = t + 2;
            for (;;) {
                int v = __hip_atomic_load(&flags[mg * 32 + l15], __ATOMIC_RELAXED, __HIP_MEMORY_SCOPE_AGENT);
                if (__all(v >= target)) break;
                __builtin_amdgcn_s_sleep(1);
            }
            FENCE_ACQ();
        }
    }

    // ---------------- epilogue ----------------
    // final h: read back from buf[ TN&1 == 0 ] (this block's own region, written by
    // this block's wave0 at t=TN-1), override cols 0,1 of inactive rows with fp32 hxy.
    if (w == 0) {
        const int r = lane >> 2, seg = lane & 3;
        const int rowg = row0 + r;
        const bool act_last = rowg < bs_lds[TN - 1];
        const size_t off = (size_t)rowg * HD + j0 + seg * 8;
        bf16x8 fh = *reinterpret_cast<const bf16x8*>(hbuf + off);
        bf16x8 fl = *reinterpret_cast<const bf16x8*>(hbuf + (size_t)BM * HD + off);
        float hv[8];
        #pragma unroll
        for (int e = 0; e < 8; ++e) {
            int jgl = j0 + seg * 8 + e;
            float v = (float)fh[e] + (float)fl[e];
            if (jb == 0 && jgl < 2 && !act_last) v = hxy[r][jgl];
            hv[e] = v;
        }
        float4 p0, p1;
        p0.x = hv[0]; p0.y = hv[1]; p0.z = hv[2]; p0.w = hv[3];
        p1.x = hv[4]; p1.y = hv[5]; p1.z = hv[6]; p1.w = hv[7];
        float* hp = out + (size_t)TN * BM * HD + off;
        *reinterpret_cast<float4*>(hp)     = p0;
        *reinterpret_cast<float4*>(hp + 4) = p1;
    }

    // final c (register state -> d_out c-section)
    if (gq == 0) {
        float* cp = out + (size_t)TN * BM * HD + (size_t)BM * HD;
        #pragma unroll
        for (int f = 0; f < 2; ++f) {
            const int jc = j0 + 8 * w + 4 * f + jjq;
            #pragma unroll
            for (int r = 0; r < 4; ++r)
                cp[(size_t)(row0 + kg * 4 + r) * HD + jc] = creg[f][r];
        }
    }
}

extern "C" void kernel_launch(void* const* d_in, const int* in_sizes, int n_in,
                              void* d_out, int out_size, void* d_ws, size_t ws_size,
                              hipStream_t stream) {
    const float* x_in = (const float*)d_in[0];
    const int*   bs   = (const int*)d_in[1];
    const float* h0   = (const float*)d_in[2];
    const float* c0   = (const float*)d_in[3];
    const float* tau  = (const float*)d_in[4];
    const float* Ww   = (const float*)d_in[5];
    const float* Wb   = (const float*)d_in[6];
    const float* Uw   = (const float*)d_in[7];
    float* out = (float*)d_out;

    int*    flags = (int*)d_ws;                      // 2048 B (16 groups x 32 ints, padded)
    __bf16* hbuf  = (__bf16*)((char*)d_ws + 2048);   // 2 bufs x 2 planes x 256 x 512 bf16 = 1 MiB

    (void)hipMemsetAsync(d_ws, 0, 2048, stream);

    hipLaunchKernelGGL(lstm_persist, dim3(256), dim3(256), 0, stream,
                       x_in, bs, h0, c0, tau, Ww, Wb, Uw, out, hbuf, flags);
}

// Round 4
// 5765.228 us; speedup vs baseline: 1.8226x; 1.8226x over previous
//
#include <hip/hip_runtime.h>

// LSTM_87771951661891: persistent kernel, fence-free cross-XCD exchange.
// Grid 256 blocks = 16 row-groups x 16 j-blocks; block = rows [mg*16,+16),
// hidden cols [jb*32,+32). U_w slice in VGPRs as MFMA B-fragments.
// h state double-buffered in d_ws as split bf16 hi/lo planes; ALL cross-block
// h traffic + flags use relaxed AGENT-scope atomics (coherent at L3 without
// fences); producer orders data->flag with raw s_waitcnt vmcnt(0).
// Per-step sync: 16 monotonic flags per row-group, spin at loop START.

#define TN 512
#define BM 256
#define HD 512
#define ID 256

typedef __attribute__((ext_vector_type(8))) __bf16 bf16x8;
typedef __attribute__((ext_vector_type(4))) float f32x4;

union U64x2 { bf16x8 v; unsigned long long q[2]; };

__device__ __forceinline__ float sigm(float x) { return 1.f / (1.f + __expf(-x)); }
__device__ __forceinline__ float tanh_fast(float x) { return 1.f - 2.f / (__expf(2.f * x) + 1.f); }

__device__ __forceinline__ unsigned long long aload64(const __bf16* p) {
    return __hip_atomic_load((const unsigned long long*)p,
                             __ATOMIC_RELAXED, __HIP_MEMORY_SCOPE_AGENT);
}
__device__ __forceinline__ void astore64(__bf16* p, unsigned long long v) {
    __hip_atomic_store((unsigned long long*)p, v,
                       __ATOMIC_RELAXED, __HIP_MEMORY_SCOPE_AGENT);
}

__global__ void __launch_bounds__(256, 1)
lstm_persist(const float* __restrict__ x_in, const int* __restrict__ bs_in,
             const float* __restrict__ h0, const float* __restrict__ c0,
             const float* __restrict__ tau_p, const float* __restrict__ Ww,
             const float* __restrict__ Wb, const float* __restrict__ Uw,
             float* __restrict__ out, __bf16* __restrict__ hbuf,
             int* __restrict__ flags)
{
    __shared__ int   bs_lds[TN];
    __shared__ float x0_lds[16][ID];     // prologue only
    __shared__ float hn_lds[16][32];     // per-step h_new tile (fp32)
    __shared__ float hxy[16][2];         // fp32 exact xcorr side-channel (jb==0, wave0-only)

    const int tid  = threadIdx.x;
    const int lane = tid & 63;
    const int w    = tid >> 6;           // wave 0..3
    const int bid  = blockIdx.x;
    const int mg   = bid >> 4;           // row-group
    const int jb   = bid & 15;           // j-block
    const int row0 = mg * 16;
    const int j0   = jb * 32;
    const int l15  = lane & 15;
    const int kg   = lane >> 4;          // 0..3 (k-chunk / row-quad id)
    const int jjq  = l15 >> 2;           // 0..3
    const int gq   = lane & 3;           // gate held pre-butterfly (0:i 1:f 2:g 3:o)
    const float tau = tau_p[0];

    // ---------------- prologue ----------------
    for (int i = tid; i < TN; i += 256) bs_lds[i] = bs_in[i];
    for (int s = tid; s < 16 * (ID / 4); s += 256) {
        int r = s >> 6, cs = s & 63;
        reinterpret_cast<float4*>(&x0_lds[r][0])[cs] =
            reinterpret_cast<const float4*>(x_in + (size_t)(row0 + r) * ID)[cs];
    }
    __syncthreads();

    // Gx = x0 @ Ww + Wb  (fp32, one-time). Column for (f, lane): gq*512 + j0 + 8w + 4f + jjq
    const int jjA   = 8 * w + jjq;
    const int ucolA = gq * HD + j0 + jjA;     // f = 0
    const int ucolB = ucolA + 4;              // f = 1
    float gxv[2][4];
    {
        float a[2][4] = {};
        for (int k = 0; k < ID; ++k) {
            float xv0 = x0_lds[kg * 4 + 0][k];
            float xv1 = x0_lds[kg * 4 + 1][k];
            float xv2 = x0_lds[kg * 4 + 2][k];
            float xv3 = x0_lds[kg * 4 + 3][k];
            float w0 = Ww[(size_t)k * 2048 + ucolA];
            float w1 = Ww[(size_t)k * 2048 + ucolB];
            a[0][0] += xv0 * w0; a[0][1] += xv1 * w0; a[0][2] += xv2 * w0; a[0][3] += xv3 * w0;
            a[1][0] += xv0 * w1; a[1][1] += xv1 * w1; a[1][2] += xv2 * w1; a[1][3] += xv3 * w1;
        }
        float b0 = Wb[ucolA], b1 = Wb[ucolB];
        #pragma unroll
        for (int r = 0; r < 4; ++r) { gxv[0][r] = a[0][r] + b0; gxv[1][r] = a[1][r] + b1; }
    }

    // U slice -> registers as MFMA B-fragments (B[k][col]: lane holds 8 k at kg*8, col l15)
    bf16x8 ub[2][16];
    #pragma unroll
    for (int f = 0; f < 2; ++f) {
        const int ucol = f ? ucolB : ucolA;
        #pragma unroll
        for (int ki = 0; ki < 16; ++ki) {
            const int kb = ki * 32 + kg * 8;
            bf16x8 v;
            #pragma unroll
            for (int e = 0; e < 8; ++e) v[e] = (__bf16)Uw[(size_t)(kb + e) * 2048 + ucol];
            ub[f][ki] = v;
        }
    }

    // c state (fp32, register-resident; quad-redundant consistent copies)
    float creg[2][4];
    #pragma unroll
    for (int f = 0; f < 2; ++f) {
        const int jc = j0 + 8 * w + 4 * f + jjq;
        #pragma unroll
        for (int r = 0; r < 4; ++r)
            creg[f][r] = c0[(size_t)(row0 + kg * 4 + r) * HD + jc];
    }

    // wave0: carried h row segment in fp32 registers + h_buf[0] init (atomic stores)
    float hprev[8];
    if (w == 0) {
        const int r = lane >> 2, seg = lane & 3;
        const float* src = h0 + (size_t)(row0 + r) * HD + j0 + seg * 8;
        float4 v0 = *reinterpret_cast<const float4*>(src);
        float4 v1 = *reinterpret_cast<const float4*>(src + 4);
        hprev[0] = v0.x; hprev[1] = v0.y; hprev[2] = v0.z; hprev[3] = v0.w;
        hprev[4] = v1.x; hprev[5] = v1.y; hprev[6] = v1.z; hprev[7] = v1.w;
        U64x2 svh, svl;
        #pragma unroll
        for (int e = 0; e < 8; ++e) {
            __bf16 hb = (__bf16)hprev[e];
            svh.v[e] = hb; svl.v[e] = (__bf16)(hprev[e] - (float)hb);
        }
        const size_t off = (size_t)(row0 + r) * HD + j0 + seg * 8;
        astore64(hbuf + off,     svh.q[0]);
        astore64(hbuf + off + 4, svh.q[1]);
        astore64(hbuf + (size_t)BM * HD + off,     svl.q[0]);
        astore64(hbuf + (size_t)BM * HD + off + 4, svl.q[1]);
        if (jb == 0 && seg == 0) { hxy[r][0] = v0.x; hxy[r][1] = v0.y; }
        asm volatile("s_waitcnt vmcnt(0)" ::: "memory");
        __builtin_amdgcn_sched_barrier(0);
        if (lane == 0)
            __hip_atomic_store(&flags[mg * 32 + jb], 1, __ATOMIC_RELAXED, __HIP_MEMORY_SCOPE_AGENT);
    }
    __syncthreads();

    // ---------------- main sequential loop ----------------
    for (int t = 0; t < TN; ++t) {
        const __bf16* base_p = hbuf + (size_t)(t & 1) * (2 * BM * HD);
        __bf16*       base_n = hbuf + (size_t)((t + 1) & 1) * (2 * BM * HD);
        const int bs_t = bs_lds[t];

        // exact fp32 xcorr recurrence for cols 0,1 (all rows), jb==0/wave0 only
        if (jb == 0 && w == 0 && l15 == 0 && t != 0) {
            #pragma unroll
            for (int r = 0; r < 4; ++r) {
                int m = kg * 4 + r;
                float xs0 = hxy[m][0], xs1 = hxy[m][1];
                hxy[m][0] = xs0 + tau * (1.5f * xs0 + 0.66666667f * xs1);
                hxy[m][1] = xs1 + tau * (-1.5f * xs0);
            }
        }

        // spin at step start: all 16 producer flags >= t+1  (buf[t&1] = h[t] ready)
        {
            const int target = t + 1;
            for (;;) {
                int v = __hip_atomic_load(&flags[mg * 32 + l15], __ATOMIC_RELAXED, __HIP_MEMORY_SCOPE_AGENT);
                if (__all(v >= target)) break;
                __builtin_amdgcn_s_sleep(1);
            }
        }

        // A fragments via relaxed agent atomic 64-bit loads (L3-coherent, no fence)
        bf16x8 ah[16], al[16];
        const __bf16* arow_h = base_p + (size_t)(row0 + l15) * HD;
        const __bf16* arow_l = arow_h + (size_t)BM * HD;
        #pragma unroll
        for (int ki = 0; ki < 16; ++ki) {
            U64x2 uh, ul;
            const __bf16* ph = arow_h + ki * 32 + kg * 8;
            const __bf16* pl = arow_l + ki * 32 + kg * 8;
            uh.q[0] = aload64(ph); uh.q[1] = aload64(ph + 4);
            ul.q[0] = aload64(pl); ul.q[1] = aload64(pl + 4);
            ah[ki] = uh.v; al[ki] = ul.v;
        }
        // read-side xcorr on k=0,1 (applies to all rows; t!=0)
        if (t != 0 && kg == 0) {
            float xs0 = (float)ah[0][0] + (float)al[0][0];
            float xs1 = (float)ah[0][1] + (float)al[0][1];
            float n0 = xs0 + tau * (1.5f * xs0 + 0.66666667f * xs1);
            float n1 = xs1 + tau * (-1.5f * xs0);
            __bf16 b0 = (__bf16)n0; ah[0][0] = b0; al[0][0] = (__bf16)(n0 - (float)b0);
            __bf16 b1 = (__bf16)n1; ah[0][1] = b1; al[0][1] = (__bf16)(n1 - (float)b1);
        }

        // gates = (A_hi + A_lo) @ U  via MFMA, acc fp32
        f32x4 acc[2] = {{0.f,0.f,0.f,0.f},{0.f,0.f,0.f,0.f}};
        #pragma unroll
        for (int ki = 0; ki < 16; ++ki) {
            acc[0] = __builtin_amdgcn_mfma_f32_16x16x32_bf16(ah[ki], ub[0][ki], acc[0], 0, 0, 0);
            acc[1] = __builtin_amdgcn_mfma_f32_16x16x32_bf16(ah[ki], ub[1][ki], acc[1], 0, 0, 0);
            acc[0] = __builtin_amdgcn_mfma_f32_16x16x32_bf16(al[ki], ub[0][ki], acc[0], 0, 0, 0);
            acc[1] = __builtin_amdgcn_mfma_f32_16x16x32_bf16(al[ki], ub[1][ki], acc[1], 0, 0, 0);
        }

        // pointwise: quad butterfly gathers i,f,g,o; update c; stash h_new
        const int qb = lane & ~3;
        #pragma unroll
        for (int f = 0; f < 2; ++f) {
            #pragma unroll
            for (int r = 0; r < 4; ++r) {
                float v  = acc[f][r] + gxv[f][r];
                float gi = __shfl(v, qb + 0);
                float gf = __shfl(v, qb + 1);
                float gg = __shfl(v, qb + 2);
                float go = __shfl(v, qb + 3);
                float cn = sigm(gf) * creg[f][r] + sigm(gi) * tanh_fast(gg);
                float hn = sigm(go) * tanh_fast(cn);
                int m = kg * 4 + r;
                bool active = (row0 + m) < bs_t;
                if (active) creg[f][r] = cn;
                if (gq == 0) {
                    int jj = 8 * w + 4 * f + jjq;
                    hn_lds[m][jj] = hn;
                    if (jb == 0 && jj < 2 && active) hxy[m][jj] = hn;
                }
            }
        }
        __syncthreads();

        // store phase (wave0): pack+store h_next (atomic), post flag, then out[t]
        if (w == 0) {
            const int r = lane >> 2, seg = lane & 3;
            const int rowg = row0 + r;
            const bool act = rowg < bs_t;
            const size_t off = (size_t)rowg * HD + j0 + seg * 8;
            float hv[8], ov[8];
            #pragma unroll
            for (int e = 0; e < 8; ++e) {
                int jgl = j0 + seg * 8 + e;
                float nv = hn_lds[r][seg * 8 + e];
                hv[e] = act ? nv : ((jgl < 2) ? hxy[r][jgl] : hprev[e]);
                ov[e] = act ? nv : 0.f;
                hprev[e] = hv[e];
            }
            U64x2 svh, svl;
            #pragma unroll
            for (int e = 0; e < 8; ++e) {
                __bf16 hb = (__bf16)hv[e];
                svh.v[e] = hb; svl.v[e] = (__bf16)(hv[e] - (float)hb);
            }
            astore64(base_n + off,     svh.q[0]);
            astore64(base_n + off + 4, svh.q[1]);
            astore64(base_n + (size_t)BM * HD + off,     svl.q[0]);
            astore64(base_n + (size_t)BM * HD + off + 4, svl.q[1]);
            asm volatile("s_waitcnt vmcnt(0)" ::: "memory");
            __builtin_amdgcn_sched_barrier(0);
            if (lane == 0)
                __hip_atomic_store(&flags[mg * 32 + jb], t + 2, __ATOMIC_RELAXED, __HIP_MEMORY_SCOPE_AGENT);

            // out[t] stores after the flag: off the inter-block critical path
            float4 q0, q1;
            q0.x = ov[0]; q0.y = ov[1]; q0.z = ov[2]; q0.w = ov[3];
            q1.x = ov[4]; q1.y = ov[5]; q1.z = ov[6]; q1.w = ov[7];
            float* op = out + (size_t)t * (BM * HD) + off;
            *reinterpret_cast<float4*>(op)     = q0;
            *reinterpret_cast<float4*>(op + 4) = q1;
        }
    }

    // ---------------- epilogue ----------------
    // final h directly from wave0's fp32 carried registers
    if (w == 0) {
        const int r = lane >> 2, seg = lane & 3;
        const size_t off = (size_t)(row0 + r) * HD + j0 + seg * 8;
        float4 p0, p1;
        p0.x = hprev[0]; p0.y = hprev[1]; p0.z = hprev[2]; p0.w = hprev[3];
        p1.x = hprev[4]; p1.y = hprev[5]; p1.z = hprev[6]; p1.w = hprev[7];
        float* hp = out + (size_t)TN * BM * HD + off;
        *reinterpret_cast<float4*>(hp)     = p0;
        *reinterpret_cast<float4*>(hp + 4) = p1;
    }

    // final c (register state -> d_out c-section)
    if (gq == 0) {
        float* cp = out + (size_t)TN * BM * HD + (size_t)BM * HD;
        #pragma unroll
        for (int f = 0; f < 2; ++f) {
            const int jc = j0 + 8 * w + 4 * f + jjq;
            #pragma unroll
            for (int r = 0; r < 4; ++r)
                cp[(size_t)(row0 + kg * 4 + r) * HD + jc] = creg[f][r];
        }
    }
}

extern "C" void kernel_launch(void* const* d_in, const int* in_sizes, int n_in,
                              void* d_out, int out_size, void* d_ws, size_t ws_size,
                              hipStream_t stream) {
    const float* x_in = (const float*)d_in[0];
    const int*   bs   = (const int*)d_in[1];
    const float* h0   = (const float*)d_in[2];
    const float* c0   = (const float*)d_in[3];
    const float* tau  = (const float*)d_in[4];
    const float* Ww   = (const float*)d_in[5];
    const float* Wb   = (const float*)d_in[6];
    const float* Uw   = (const float*)d_in[7];
    float* out = (float*)d_out;

    int*    flags = (int*)d_ws;                      // 2048 B (16 groups x 32 ints, padded)
    __bf16* hbuf  = (__bf16*)((char*)d_ws + 2048);   // 2 bufs x 2 planes x 256 x 512 bf16 = 1 MiB

    (void)hipMemsetAsync(d_ws, 0, 2048, stream);

    hipLaunchKernelGGL(lstm_persist, dim3(256), dim3(256), 0, stream,
                       x_in, bs, h0, c0, tau, Ww, Wb, Uw, out, hbuf, flags);
}

// Round 5
// 4121.663 us; speedup vs baseline: 2.5494x; 1.3988x over previous
//
#include <hip/hip_runtime.h>

// LSTM_87771951661891: persistent kernel, wave-autonomous steps.
// Grid 256 blocks = 16 row-groups x 16 j-blocks; block = rows [mg*16,+16),
// hidden cols [jb*32,+32); each wave owns 8 hidden cols (cols j0+8w..+8).
// Swapped-operand MFMA: acc = mfma(Ut_frag, h_frag) -> lane l15 = row m,
// acc[f][reg] = gate reg of hidden col j0+8w+4f+kg. Pointwise is lane-local.
// h state (bf16, single plane) double-buffered in d_ws; cross-block traffic
// via relaxed AGENT-scope atomics (no fences); data->flag ordered by
// s_waitcnt vmcnt(0). Per-(block,wave) flags: 64 per row-group, monotonic.
// Exactness of inactive-row carry: fp32 hprev (per store-lane) + fp32 hxy
// side channel for the xcorr-amplified cols 0,1 (block jb==0, wave 0).

#define TN 512
#define BM 256
#define HD 512
#define ID 256

typedef __attribute__((ext_vector_type(8))) __bf16 bf16x8;
typedef __attribute__((ext_vector_type(4))) __bf16 bf16x4;
typedef __attribute__((ext_vector_type(4))) float f32x4;

union U64x2 { bf16x8 v; unsigned long long q[2]; };
union U64x1 { bf16x4 v; unsigned long long q; };

__device__ __forceinline__ float sigm(float x) { return 1.f / (1.f + __expf(-x)); }
__device__ __forceinline__ float tanh_fast(float x) { return 1.f - 2.f / (__expf(2.f * x) + 1.f); }

__device__ __forceinline__ unsigned long long aload64(const __bf16* p) {
    return __hip_atomic_load((const unsigned long long*)p,
                             __ATOMIC_RELAXED, __HIP_MEMORY_SCOPE_AGENT);
}
__device__ __forceinline__ void astore64(__bf16* p, unsigned long long v) {
    __hip_atomic_store((unsigned long long*)p, v,
                       __ATOMIC_RELAXED, __HIP_MEMORY_SCOPE_AGENT);
}

__global__ void __launch_bounds__(256, 1)
lstm_persist(const float* __restrict__ x_in, const int* __restrict__ bs_in,
             const float* __restrict__ h0, const float* __restrict__ c0,
             const float* __restrict__ tau_p, const float* __restrict__ Ww,
             const float* __restrict__ Wb, const float* __restrict__ Uw,
             float* __restrict__ out, __bf16* __restrict__ hbuf,
             int* __restrict__ flags)
{
    __shared__ int   bs_lds[TN];
    __shared__ float x0_lds[16][ID + 1];      // padded (bank-conflict-free)
    __shared__ float hn_patch[4][16][9];      // per-wave h_new transpose patch

    const int tid  = threadIdx.x;
    const int lane = tid & 63;
    const int w    = tid >> 6;           // wave 0..3
    const int bid  = blockIdx.x;
    const int mg   = bid >> 4;           // row-group
    const int jb   = bid & 15;           // j-block
    const int row0 = mg * 16;
    const int j0   = jb * 32;
    const int l15  = lane & 15;          // MFMA row (m) for B-frag / output col
    const int kg   = lane >> 4;          // k-chunk id; also hidden-subcol in output
    const int gq   = lane & 3;           // ub build: gate index of MFMA-col l15
    const int jjq  = l15 >> 2;           // ub build: hidden-subcol of MFMA-col l15
    const float tau = tau_p[0];

    // ---------------- prologue ----------------
    for (int i = tid; i < TN; i += 256) bs_lds[i] = bs_in[i];
    for (int s = tid; s < 16 * (ID / 4); s += 256) {
        int r = s >> 6, cs = s & 63;
        *reinterpret_cast<float4*>(&x0_lds[r][cs * 4]) =
            reinterpret_cast<const float4*>(x_in + (size_t)(row0 + r) * ID)[cs];
    }
    __syncthreads();

    // Gx = x0 @ Ww + Wb for this lane's 8 output gates:
    // (row m=l15, col = g*512 + j0 + 8w + 4f + kg), f in {0,1}, g in {0..3}
    float gxv[2][4];
    {
        float a[2][4] = {};
        const int cbase = j0 + 8 * w + kg;
        for (int k = 0; k < ID; ++k) {
            float xv = x0_lds[l15][k];
            const float* wr = Ww + (size_t)k * 2048;
            #pragma unroll
            for (int g = 0; g < 4; ++g) {
                a[0][g] += xv * wr[g * HD + cbase];
                a[1][g] += xv * wr[g * HD + cbase + 4];
            }
        }
        #pragma unroll
        for (int g = 0; g < 4; ++g) {
            gxv[0][g] = a[0][g] + Wb[g * HD + j0 + 8 * w + kg];
            gxv[1][g] = a[1][g] + Wb[g * HD + j0 + 8 * w + kg + 4];
        }
    }

    // U slice -> registers. Fragment: lane holds k-slice kg*8+e of MFMA-col l15,
    // col(l15) = gq*512 + j0 + 8w + 4f + jjq  (used as A-operand = U^T)
    bf16x8 ub[2][16];
    #pragma unroll
    for (int f = 0; f < 2; ++f) {
        const int ucol = gq * HD + j0 + 8 * w + 4 * f + jjq;
        #pragma unroll
        for (int ki = 0; ki < 16; ++ki) {
            const int kb = ki * 32 + kg * 8;
            bf16x8 v;
            #pragma unroll
            for (int e = 0; e < 8; ++e) v[e] = (__bf16)Uw[(size_t)(kb + e) * 2048 + ucol];
            ub[f][ki] = v;
        }
    }

    // c state: lane-local, (row m=l15, col j0+8w+4f+kg)
    float creg[2];
    #pragma unroll
    for (int f = 0; f < 2; ++f)
        creg[f] = c0[(size_t)(row0 + l15) * HD + j0 + 8 * w + 4 * f + kg];

    // store-lane setup (lane<32): r=lane>>1, s=lane&1 -> 4 cols jc..jc+3
    const int sr = lane >> 1, ss = lane & 1;
    const int jc = j0 + 8 * w + 4 * ss;
    const bool is_store = (lane < 32);
    const bool owner = (jb == 0) && (w == 0) && (ss == 0) && is_store; // cols 0..3, hxy for 0,1
    float hprev[4] = {0.f, 0.f, 0.f, 0.f};
    float hxy0 = 0.f, hxy1 = 0.f;

    if (is_store) {
        float4 v = *reinterpret_cast<const float4*>(h0 + (size_t)(row0 + sr) * HD + jc);
        hprev[0] = v.x; hprev[1] = v.y; hprev[2] = v.z; hprev[3] = v.w;
        if (owner) { hxy0 = v.x; hxy1 = v.y; }
        U64x1 sv;
        #pragma unroll
        for (int c = 0; c < 4; ++c) sv.v[c] = (__bf16)hprev[c];
        astore64(hbuf + (size_t)(row0 + sr) * HD + jc, sv.q);
    }
    asm volatile("s_waitcnt vmcnt(0)" ::: "memory");
    __builtin_amdgcn_sched_barrier(0);
    if (lane == 0)
        __hip_atomic_store(&flags[mg * 64 + jb * 4 + w], 1,
                           __ATOMIC_RELAXED, __HIP_MEMORY_SCOPE_AGENT);

    // ---------------- main sequential loop ----------------
    for (int t = 0; t < TN; ++t) {
        const __bf16* base_p = hbuf + (size_t)(t & 1) * (BM * HD);
        __bf16*       base_n = hbuf + (size_t)((t + 1) & 1) * (BM * HD);
        const int bs_t = bs_lds[t];

        // fp32 xcorr side-channel advance (owner lanes; harmless elsewhere)
        if (t != 0) {
            float xs0 = hxy0, xs1 = hxy1;
            hxy0 = xs0 + tau * (1.5f * xs0 + 0.66666667f * xs1);
            hxy1 = xs1 + tau * (-1.5f * xs0);
        }

        // spin: all 64 producer-wave flags of this row-group >= t+1
        for (;;) {
            int v = __hip_atomic_load(&flags[mg * 64 + lane],
                                      __ATOMIC_RELAXED, __HIP_MEMORY_SCOPE_AGENT);
            if (__all(v >= t + 1)) break;
            __builtin_amdgcn_s_sleep(1);
        }

        // h fragments (B-operand): lane l15 = row m, k-slice kg*8..+8 per ki
        bf16x8 ah[16];
        const __bf16* arow = base_p + (size_t)(row0 + l15) * HD + kg * 8;
        #pragma unroll
        for (int ki = 0; ki < 16; ++ki) {
            U64x2 u;
            u.q[0] = aload64(arow + ki * 32);
            u.q[1] = aload64(arow + ki * 32 + 4);
            ah[ki] = u.v;
        }
        // read-side xcorr on k=0,1 (all rows; t!=0), fp32
        if (t != 0 && kg == 0) {
            float xs0 = (float)ah[0][0];
            float xs1 = (float)ah[0][1];
            ah[0][0] = (__bf16)(xs0 + tau * (1.5f * xs0 + 0.66666667f * xs1));
            ah[0][1] = (__bf16)(xs1 + tau * (-1.5f * xs0));
        }

        // gates = U^T x h^T  (swapped operands): acc[f][g] for (m=l15, col 8w+4f+kg)
        f32x4 acc0 = {0.f, 0.f, 0.f, 0.f}, acc1 = {0.f, 0.f, 0.f, 0.f};
        #pragma unroll
        for (int ki = 0; ki < 16; ++ki) {
            acc0 = __builtin_amdgcn_mfma_f32_16x16x32_bf16(ub[0][ki], ah[ki], acc0, 0, 0, 0);
            acc1 = __builtin_amdgcn_mfma_f32_16x16x32_bf16(ub[1][ki], ah[ki], acc1, 0, 0, 0);
        }

        // pointwise: fully lane-local (4 gates per hidden unit in-register)
        const bool act_m = (row0 + l15) < bs_t;
        #pragma unroll
        for (int f = 0; f < 2; ++f) {
            const f32x4 a = f ? acc1 : acc0;
            float gi = a[0] + gxv[f][0];
            float gf = a[1] + gxv[f][1];
            float gg = a[2] + gxv[f][2];
            float go = a[3] + gxv[f][3];
            float cn = sigm(gf) * creg[f] + sigm(gi) * tanh_fast(gg);
            float hn = sigm(go) * tanh_fast(cn);
            if (act_m) creg[f] = cn;
            hn_patch[w][l15][4 * f + kg] = hn;
        }

        // wave-local transpose barrier (no __syncthreads: same-wave LDS ordering)
        asm volatile("s_waitcnt lgkmcnt(0)" ::: "memory");
        __builtin_amdgcn_sched_barrier(0);

        // store phase: lanes 0..31, row sr, cols jc..jc+3
        if (is_store) {
            const bool act_r = (row0 + sr) < bs_t;
            float hn0 = hn_patch[w][sr][4 * ss + 0];
            float hn1 = hn_patch[w][sr][4 * ss + 1];
            float hn2 = hn_patch[w][sr][4 * ss + 2];
            float hn3 = hn_patch[w][sr][4 * ss + 3];
            float hv[4];
            hv[0] = act_r ? hn0 : hprev[0];
            hv[1] = act_r ? hn1 : hprev[1];
            hv[2] = act_r ? hn2 : hprev[2];
            hv[3] = act_r ? hn3 : hprev[3];
            if (owner) {
                if (act_r) { hxy0 = hn0; hxy1 = hn1; }
                else       { hv[0] = hxy0; hv[1] = hxy1; }
            }
            #pragma unroll
            for (int c = 0; c < 4; ++c) hprev[c] = hv[c];
            U64x1 sv;
            #pragma unroll
            for (int c = 0; c < 4; ++c) sv.v[c] = (__bf16)hv[c];
            astore64(base_n + (size_t)(row0 + sr) * HD + jc, sv.q);
            asm volatile("s_waitcnt vmcnt(0)" ::: "memory");
            __builtin_amdgcn_sched_barrier(0);
            if (lane == 0)
                __hip_atomic_store(&flags[mg * 64 + jb * 4 + w], t + 2,
                                   __ATOMIC_RELAXED, __HIP_MEMORY_SCOPE_AGENT);
            // outputs[t] (off the inter-block critical path)
            float4 q;
            q.x = act_r ? hn0 : 0.f; q.y = act_r ? hn1 : 0.f;
            q.z = act_r ? hn2 : 0.f; q.w = act_r ? hn3 : 0.f;
            *reinterpret_cast<float4*>(out + (size_t)t * (BM * HD)
                                       + (size_t)(row0 + sr) * HD + jc) = q;
        }
    }

    // ---------------- epilogue ----------------
    // final h from fp32 hprev (store-lanes)
    if (is_store) {
        float4 p;
        p.x = hprev[0]; p.y = hprev[1]; p.z = hprev[2]; p.w = hprev[3];
        *reinterpret_cast<float4*>(out + (size_t)TN * BM * HD
                                   + (size_t)(row0 + sr) * HD + jc) = p;
    }
    // final c from lane-local creg
    {
        float* cp = out + (size_t)TN * BM * HD + (size_t)BM * HD;
        #pragma unroll
        for (int f = 0; f < 2; ++f)
            cp[(size_t)(row0 + l15) * HD + j0 + 8 * w + 4 * f + kg] = creg[f];
    }
}

extern "C" void kernel_launch(void* const* d_in, const int* in_sizes, int n_in,
                              void* d_out, int out_size, void* d_ws, size_t ws_size,
                              hipStream_t stream) {
    const float* x_in = (const float*)d_in[0];
    const int*   bs   = (const int*)d_in[1];
    const float* h0   = (const float*)d_in[2];
    const float* c0   = (const float*)d_in[3];
    const float* tau  = (const float*)d_in[4];
    const float* Ww   = (const float*)d_in[5];
    const float* Wb   = (const float*)d_in[6];
    const float* Uw   = (const float*)d_in[7];
    float* out = (float*)d_out;

    int*    flags = (int*)d_ws;                      // 16 groups x 64 flags = 4 KB
    __bf16* hbuf  = (__bf16*)((char*)d_ws + 4096);   // 2 bufs x 256 x 512 bf16 = 512 KB

    (void)hipMemsetAsync(d_ws, 0, 4096, stream);

    hipLaunchKernelGGL(lstm_persist, dim3(256), dim3(256), 0, stream,
                       x_in, bs, h0, c0, tau, Ww, Wb, Uw, out, hbuf, flags);
}